// Round 2
// baseline (2123.362 us; speedup 1.0000x reference)
//
#include <hip/hip_runtime.h>
#include <hip/hip_bf16.h>
#include <stdint.h>

// Problem constants
#define BB 64
#define P0 729
#define CC 1152
#define HD 72        // CC / 16 heads
#define NHEAD 16
#define HH 3584
#define TT 128
#define NSTR 365     // max src count, stride for per-round index arrays
#define SCB 384      // padded row stride for partial-argmax buffers
#define MAXCB 6      // max column blocks (ceil(364/64))

typedef __hip_bfloat16 bf16;
typedef unsigned short u16;
typedef __attribute__((ext_vector_type(8))) short short8;
typedef __attribute__((ext_vector_type(4))) float floatx4;

__device__ inline u16 f2bf(float v) {
  bf16 h = __float2bfloat16(v);
  return *(u16*)&h;
}

__device__ inline void load_lds16(const void* g, void* l) {
  __builtin_amdgcn_global_load_lds(
      (const __attribute__((address_space(1))) uint32_t*)g,
      (__attribute__((address_space(3))) uint32_t*)l, 16, 0, 0);
}

// ---------------- init: fp64 head-mean of (x+pos), amap = identity ----------------
__global__ __launch_bounds__(128)
void k_init(const float* __restrict__ x, const float* __restrict__ pos,
            double* __restrict__ mo, int* __restrict__ amap) {
  __shared__ float xs[CC], ps[CC];
  int bp = blockIdx.x;           // b*729+p
  int p = bp % P0;
  int tid = threadIdx.x;         // 128
  const float4* xr = (const float4*)(x + (size_t)bp * CC);
  const float4* pr = (const float4*)(pos + (size_t)p * CC);
  for (int idx = tid; idx < CC / 4; idx += 128) {
    ((float4*)xs)[idx] = xr[idx];
    ((float4*)ps)[idx] = pr[idx];
  }
  __syncthreads();
  if (tid < HD) {
    double s = 0.0;
    #pragma unroll
    for (int h = 0; h < NHEAD; ++h) {
      int c = h * HD + tid;
      s += (double)xs[c] + (double)ps[c];
    }
    mo[(size_t)bp * HD + tid] = s * (1.0 / 16.0);
  }
  if (tid == 0) amap[bp] = p;
}

// ---------------- 1/||m|| per token (fp64) ----------------
__global__ void k_rnorm(const double* __restrict__ m, double* __restrict__ rn, int t) {
  int bi = blockIdx.x;           // b*t + i
  int lane = threadIdx.x;        // 64
  const double* row = m + (size_t)bi * HD;
  double v = 0.0;
  if (lane < HD) { double a = row[lane]; v = a * a; }
  if (lane < HD - 64) { double a = row[lane + 64]; v += a * a; }
  for (int off = 32; off; off >>= 1) v += __shfl_down(v, off, 64);
  if (lane == 0) {
    int b = bi / t, i = bi % t;
    rn[b * P0 + i] = 1.0 / sqrt(v);
  }
}

// ---------------- fp64 scores, 64x64 tile, 4x4 per thread ----------------
// Emits per-column-strip (max, first-argmax) partials; k_colred folds strips.
__global__ __launch_bounds__(256)
void k_score2(const double* __restrict__ m, const double* __restrict__ rn,
              double* __restrict__ pmax, int* __restrict__ pidx,
              int t, int s, int d) {
  __shared__ double sL[64][37];
  __shared__ double sD[64][37];
  int b = blockIdx.z;
  int i0 = blockIdx.x * 64, j0 = blockIdx.y * 64;
  int tid = threadIdx.x;
  int tx = tid & 15, ty = tid >> 4;
  double acc[4][4] = {};
  for (int kc = 0; kc < HD; kc += 36) {
    for (int idx = tid; idx < 64 * 36; idx += 256) {
      int row = idx / 36, k = idx - row * 36;
      int i = i0 + row;
      sL[row][k] = (i < s) ? m[((size_t)b * t + 2 * i) * HD + kc + k] : 0.0;
      int j = j0 + row;
      sD[row][k] = (j < d) ? m[((size_t)b * t + 2 * j + 1) * HD + kc + k] : 0.0;
    }
    __syncthreads();
    #pragma unroll 6
    for (int k = 0; k < 36; ++k) {
      double la[4], ld[4];
      #pragma unroll
      for (int a = 0; a < 4; ++a) la[a] = sL[ty + 16 * a][k];
      #pragma unroll
      for (int c = 0; c < 4; ++c) ld[c] = sD[tx + 16 * c][k];
      #pragma unroll
      for (int a = 0; a < 4; ++a)
        #pragma unroll
        for (int c = 0; c < 4; ++c)
          acc[a][c] += la[a] * ld[c];
    }
    __syncthreads();
  }
  #pragma unroll
  for (int a = 0; a < 4; ++a) {
    int i = i0 + ty + 16 * a;
    double rni = (i < s) ? rn[b * P0 + 2 * i] : 0.0;
    double best = -1e300; int bj = 0x7fffffff;
    #pragma unroll
    for (int c = 0; c < 4; ++c) {
      int j = j0 + tx + 16 * c;                       // ascending j per c
      double sc = (j < d) ? acc[a][c] * rni * rn[b * P0 + 2 * j + 1] : -1e300;
      if (sc > best) { best = sc; bj = j; }           // strict > keeps first max
    }
    for (int off = 8; off; off >>= 1) {
      double ov = __shfl_down(best, off, 16);
      int oj = __shfl_down(bj, off, 16);
      if (ov > best || (ov == best && oj < bj)) { best = ov; bj = oj; }
    }
    if (tx == 0 && i < s) {
      pmax[((size_t)b * MAXCB + blockIdx.y) * SCB + i] = best;
      pidx[((size_t)b * MAXCB + blockIdx.y) * SCB + i] = bj;
    }
  }
}

// ---------------- fold column-strip partials (ascending j, first-max) ----------
__global__ void k_colred(const double* __restrict__ pmax, const int* __restrict__ pidx,
                         double* __restrict__ nmax, int* __restrict__ nidx,
                         int s, int ncb) {
  int b = blockIdx.x, i = threadIdx.x;   // 512 >= s
  if (i >= s) return;
  double best = -1e300; int bj = 0x7fffffff;
  for (int cb = 0; cb < ncb; ++cb) {
    double v = pmax[((size_t)b * MAXCB + cb) * SCB + i];
    int j = pidx[((size_t)b * MAXCB + cb) * SCB + i];
    if (v > best) { best = v; bj = j; }  // cb ascending = j ascending
  }
  nmax[b * NSTR + i] = best; nidx[b * NSTR + i] = bj;
}

// ---------------- stable descending argsort (bitonic, idx tiebreak) ----------------
template <int SZ>
__global__ __launch_bounds__(512)
void k_sort(const double* __restrict__ nmax, int* __restrict__ eidx, int s) {
  __shared__ double v[SZ];
  __shared__ int ix[SZ];
  int b = blockIdx.x, tid = threadIdx.x;
  if (tid < s) { v[tid] = nmax[b * NSTR + tid]; ix[tid] = tid; }
  else { v[tid] = -1e308; ix[tid] = 1024 + tid; }
  __syncthreads();
  for (int k = 2; k <= SZ; k <<= 1)
    for (int j = k >> 1; j > 0; j >>= 1) {
      int l = tid ^ j;
      if (l > tid) {
        double va = v[tid], vb = v[l]; int ia = ix[tid], ib = ix[l];
        bool b_before_a = (vb > va) || (vb == va && ib < ia);
        bool a_before_b = (va > vb) || (va == vb && ia < ib);
        bool dir = ((tid & k) == 0);
        bool sw = dir ? b_before_a : a_before_b;
        if (sw) { v[tid] = vb; v[l] = va; ix[tid] = ib; ix[l] = ia; }
      }
      __syncthreads();
    }
  if (tid < s) eidx[b * NSTR + tid] = ix[tid];
}

// ---------------- compose per-round old->new map into amap (orig token -> slot) ----
__global__ __launch_bounds__(512)
void k_mapround(const int* __restrict__ eidx, const int* __restrict__ nidx,
                int* __restrict__ amap, int t, int s, int r, int unm) {
  __shared__ int pos_of[NSTR];
  __shared__ int rmap[P0];
  int b = blockIdx.x, tid = threadIdx.x;
  for (int q = tid; q < s; q += 512) pos_of[eidx[b * NSTR + q]] = q;
  __syncthreads();
  for (int j = tid; j < t; j += 512) {
    int nm;
    if (j & 1) {
      nm = unm + (j >> 1);                      // odd token = dst jd -> unm + jd
    } else {
      int i = j >> 1;                           // even token = src i
      int q = pos_of[i];
      nm = (q >= r) ? (q - r)                   // unmerged: position in unm block
                    : (unm + nidx[b * NSTR + i]); // merged into its dst
    }
    rmap[j] = nm;
  }
  __syncthreads();
  for (int p = tid; p < P0; p += 512) {
    int cur = amap[b * P0 + p];
    amap[b * P0 + p] = rmap[cur];
  }
}

// ---------------- fp64 metric merge: gather then scatter-add ----------------
__global__ void k_gather_d(const double* __restrict__ mo, double* __restrict__ mn,
                           const int* __restrict__ eidx,
                           int t, int r, int unm, int tnew) {
  size_t idx = (size_t)blockIdx.x * 256 + threadIdx.x;
  size_t total = (size_t)BB * tnew * HD;
  if (idx >= total) return;
  int k = idx % HD;
  int o = (idx / HD) % tnew;
  int b = idx / ((size_t)HD * tnew);
  int tok = (o < unm) ? 2 * eidx[b * NSTR + r + o] : 2 * (o - unm) + 1;
  mn[idx] = mo[((size_t)b * t + tok) * HD + k];
}

__global__ void k_scatter_d(const double* __restrict__ mo, double* __restrict__ mn,
                            const int* __restrict__ eidx, const int* __restrict__ nidx,
                            int t, int r, int unm, int tnew) {
  size_t idx = (size_t)blockIdx.x * 256 + threadIdx.x;
  size_t total = (size_t)BB * r * HD;
  if (idx >= total) return;
  int k = idx % HD;
  int q = (idx / HD) % r;
  int b = idx / ((size_t)HD * r);
  int si = eidx[b * NSTR + q];
  int di = nidx[b * NSTR + si];
  atomicAdd(&mn[((size_t)b * tnew + unm + di) * HD + k],
            mo[((size_t)b * t + 2 * si) * HD + k]);
}

// ---------------- sizes: per-batch histogram of amap ----------------
__global__ __launch_bounds__(256)
void k_sizes(const int* __restrict__ amap, int* __restrict__ sizes) {
  __shared__ int cnt[TT];
  int b = blockIdx.x, tid = threadIdx.x;
  if (tid < TT) cnt[tid] = 0;
  __syncthreads();
  for (int p = tid; p < P0; p += 256) atomicAdd(&cnt[amap[b * P0 + p]], 1);
  __syncthreads();
  if (tid < TT) sizes[b * TT + tid] = cnt[tid];
}

// ---------------- clear fp32 accumulator ----------------
__global__ __launch_bounds__(256)
void k_clear(float4* __restrict__ a, int n4) {
  int stride = gridDim.x * 256;
  for (int i = blockIdx.x * 256 + threadIdx.x; i < n4; i += stride)
    a[i] = make_float4(0.f, 0.f, 0.f, 0.f);
}

// ---------------- scatter-add: stream (x+pos) rows into accum[amap] ----------------
// One wave per original token row: coalesced float4 reads, 4-5 loads in flight
// per lane, uniform amap lookup, fp32 atomics (contention ~ avg 5.7 rows/slot).
__global__ __launch_bounds__(256)
void k_scatter_rows(const float* __restrict__ x, const float* __restrict__ pos,
                    const int* __restrict__ amap, float* __restrict__ accum) {
  int w = threadIdx.x >> 6, lane = threadIdx.x & 63;
  int bp = blockIdx.x * 4 + w;             // BB*P0 = 46656 = 4*11664 exact
  int b = bp / P0, p = bp - b * P0;
  int o = amap[bp];                        // uniform per wave -> scalar load
  const float4* xr = (const float4*)(x + (size_t)bp * CC);
  const float4* pr = (const float4*)(pos + (size_t)p * CC);
  float* arow = accum + ((size_t)b * TT + o) * CC;
  #pragma unroll
  for (int t = 0; t < 4; ++t) {
    int idx = lane + t * 64;
    float4 v = xr[idx], q = pr[idx];
    atomicAdd(&arow[4 * idx + 0], v.x + q.x);
    atomicAdd(&arow[4 * idx + 1], v.y + q.y);
    atomicAdd(&arow[4 * idx + 2], v.z + q.z);
    atomicAdd(&arow[4 * idx + 3], v.w + q.w);
  }
  if (lane < 32) {
    int idx = lane + 256;                  // CC/4 = 288 columns
    float4 v = xr[idx], q = pr[idx];
    atomicAdd(&arow[4 * idx + 0], v.x + q.x);
    atomicAdd(&arow[4 * idx + 1], v.y + q.y);
    atomicAdd(&arow[4 * idx + 2], v.z + q.z);
    atomicAdd(&arow[4 * idx + 3], v.w + q.w);
  }
}

// ---------------- normalize: accum / size -> bf16 ----------------
__global__ __launch_bounds__(256)
void k_normalize(const float* __restrict__ accum, const int* __restrict__ szs,
                 bf16* __restrict__ xb) {
  int w = threadIdx.x >> 6, lane = threadIdx.x & 63;
  int row = blockIdx.x * 4 + w;            // BB*TT = 8192 = 4*2048 exact
  float inv = 1.0f / (float)szs[row];
  const float4* ar = (const float4*)(accum + (size_t)row * CC);
  ushort4* orow = (ushort4*)(xb + (size_t)row * CC);
  #pragma unroll
  for (int t = 0; t < 4; ++t) {
    int idx = lane + t * 64;
    float4 v = ar[idx];
    ushort4 pk;
    pk.x = f2bf(v.x * inv); pk.y = f2bf(v.y * inv);
    pk.z = f2bf(v.z * inv); pk.w = f2bf(v.w * inv);
    orow[idx] = pk;
  }
  if (lane < 32) {
    int idx = lane + 256;
    float4 v = ar[idx];
    ushort4 pk;
    pk.x = f2bf(v.x * inv); pk.y = f2bf(v.y * inv);
    pk.z = f2bf(v.z * inv); pk.w = f2bf(v.w * inv);
    orow[idx] = pk;
  }
}

// ---------------- transpose + cast weights: (K,N) fp32 -> (N,K) bf16 ----------------
__global__ void k_transpose(const float* __restrict__ w, bf16* __restrict__ wt,
                            int K, int N) {
  __shared__ float tile[32][33];
  int n0 = blockIdx.x * 32, k0 = blockIdx.y * 32;
  int tx = threadIdx.x, ty = threadIdx.y;   // 32 x 8
  #pragma unroll
  for (int yy = 0; yy < 32; yy += 8)
    tile[ty + yy][tx] = w[(size_t)(k0 + ty + yy) * N + n0 + tx];
  __syncthreads();
  #pragma unroll
  for (int yy = 0; yy < 32; yy += 8)
    wt[(size_t)(n0 + ty + yy) * K + k0 + tx] = __float2bfloat16(tile[tx][ty + yy]);
}

// =====================================================================
// 256x256 8-phase bf16 MFMA GEMM (T2 swizzle + T3/T4 counted vmcnt + T5)
// A (M,K) row-major bf16, Bt (N,K) row-major bf16.
// 512 threads = 8 waves (2 M x 4 N); per-wave 64x32 piece of each of the
// four 128x128 C-quadrants. BK=64, double-buffered LDS (128 KiB), one
// half-tile (128x64) staged per phase, vmcnt(6) once per K-tile at phase 4.
// LDS swizzle: col16 ^= (row&7) (16B granularity); inverse applied to the
// GLOBAL source address so global_load_lds' linear dest stays legal.
// EPI 0: out = bf16(gelu_exact(acc + bias))   EPI 1: out = fp32(acc + bias)
// =====================================================================

#define SBAR __builtin_amdgcn_sched_barrier(0)

#define STAGE_A(BUF, HHF, KT) do {                                        \
    int ktc_ = (KT) < nkt ? (KT) : nkt - 1;                               \
    const u16* s_ = gA + (size_t)(HHF) * 128 * K + ktc_ * 64;             \
    u16* d_ = dA + (BUF) * 16384 + (HHF) * 8192;                          \
    load_lds16(s_, d_);                                                   \
    load_lds16(s_ + (size_t)64 * K, d_ + 4096);                           \
  } while (0)

#define STAGE_B(BUF, HHF, KT) do {                                        \
    int ktc_ = (KT) < nkt ? (KT) : nkt - 1;                               \
    const u16* s_ = gB + (size_t)(HHF) * 128 * K + ktc_ * 64;             \
    u16* d_ = dB + (BUF) * 16384 + (HHF) * 8192;                          \
    load_lds16(s_, d_);                                                   \
    load_lds16(s_ + (size_t)64 * K, d_ + 4096);                           \
  } while (0)

#define LOADA(QA) do {                                                    \
    _Pragma("unroll")                                                     \
    for (int f_ = 0; f_ < 4; ++f_) {                                      \
      const u16* p_ = Ab + ((QA) * 128 + wr64 + f_ * 16 + lrow) * 64;     \
      af[f_][0] = *(const short8*)(p_ + swo0);                            \
      af[f_][1] = *(const short8*)(p_ + swo1);                            \
    }                                                                     \
  } while (0)

#define LOADB(QB) do {                                                    \
    _Pragma("unroll")                                                     \
    for (int g_ = 0; g_ < 2; ++g_) {                                      \
      const u16* p_ = Bb + ((QB) * 128 + wc32 + g_ * 16 + lrow) * 64;     \
      bfr[g_][0] = *(const short8*)(p_ + swo0);                           \
      bfr[g_][1] = *(const short8*)(p_ + swo1);                           \
    }                                                                     \
  } while (0)

#define DO_MFMA(QA, QB) do {                                              \
    _Pragma("unroll")                                                     \
    for (int ks_ = 0; ks_ < 2; ++ks_)                                     \
      _Pragma("unroll")                                                   \
      for (int f_ = 0; f_ < 4; ++f_)                                      \
        _Pragma("unroll")                                                 \
        for (int g_ = 0; g_ < 2; ++g_)                                    \
          acc[QA][QB][f_][g_] = __builtin_amdgcn_mfma_f32_16x16x32_bf16(  \
              af[f_][ks_], bfr[g_][ks_], acc[QA][QB][f_][g_], 0, 0, 0);   \
  } while (0)

#define MIDBAR() do {                                                     \
    SBAR;                                                                 \
    __builtin_amdgcn_s_barrier();                                         \
    asm volatile("s_waitcnt lgkmcnt(0)" ::: "memory");                    \
    SBAR;                                                                 \
    __builtin_amdgcn_s_setprio(1);                                        \
  } while (0)

#define ENDBAR() do {                                                     \
    __builtin_amdgcn_s_setprio(0);                                        \
    SBAR;                                                                 \
    __builtin_amdgcn_s_barrier();                                         \
    SBAR;                                                                 \
  } while (0)

#define ENDBAR_VM() do {                                                  \
    __builtin_amdgcn_s_setprio(0);                                        \
    SBAR;                                                                 \
    asm volatile("s_waitcnt vmcnt(6)" ::: "memory");                      \
    SBAR;                                                                 \
    __builtin_amdgcn_s_barrier();                                         \
    SBAR;                                                                 \
  } while (0)

template <int EPI>
__global__ __launch_bounds__(512, 2)
void k_gemm(const u16* __restrict__ A, const u16* __restrict__ Bt,
            const float* __restrict__ bias, void* __restrict__ Cout,
            int M, int N, int K) {
  __shared__ u16 sAall[32768];   // [buf][256 rows][64] bf16, 64 KiB
  __shared__ u16 sBall[32768];   // 64 KiB
  (void)M;
  const int tid = threadIdx.x;
  const int m0 = blockIdx.y * 256, n0 = blockIdx.x * 256;
  const int wave = tid >> 6, lane = tid & 63;
  const int wr64 = (wave >> 2) * 64;   // wave's rows within a quadrant
  const int wc32 = (wave & 3) * 32;    // wave's cols within a quadrant
  const int quad = lane >> 4, lrow = lane & 15;
  const int sw = lrow & 7;             // row&7 == lrow&7 for all frag rows
  const int swo0 = ((quad ^ sw)) << 3;        // ks=0 swizzled u16 offset
  const int swo1 = (((quad | 4) ^ sw)) << 3;  // ks=1
  const int nkt = K >> 6;              // K-tiles of 64

  // staging geometry: thread covers rows r and r+64 of a 128x64 half-tile;
  // source col16 pre-swizzled so linear LDS dest + swizzled ds_read agree.
  const int r = tid >> 3;
  const int c16 = (tid & 7) ^ (r & 7);
  const u16* gA = A + (size_t)(m0 + r) * K + c16 * 8;
  const u16* gB = Bt + (size_t)(n0 + r) * K + c16 * 8;
  u16* dA = sAall + (tid << 3);
  u16* dB = sBall + (tid << 3);

  floatx4 acc[2][2][4][2] = {};   // [qa][qb][mfrag][nfrag]
  short8 af[4][2], bfr[2][2];     // [frag][kstep]

  // prologue: tile0 fully (A0,B1,A1,B0) + tile1 all but B0 -> 14 loads;
  // vmcnt(6) leaves exactly tile1's {A0,B1,A1} in flight (steady state).
  STAGE_A(0, 0, 0); STAGE_B(0, 1, 0); STAGE_A(0, 1, 0); STAGE_B(0, 0, 0);
  STAGE_A(1, 0, 1); STAGE_B(1, 1, 1); STAGE_A(1, 1, 1);
  SBAR;
  asm volatile("s_waitcnt vmcnt(6)" ::: "memory");
  SBAR;
  __builtin_amdgcn_s_barrier();
  SBAR;

  for (int t = 0; t < nkt; ++t) {
    const int bb = t & 1;
    const u16* Ab = sAall + bb * 16384;
    const u16* Bb = sBall + bb * 16384;
    // phase 1: quadrant (0,0); stage B-half0 of tile t+1 into other buffer
    LOADA(0); LOADB(0);
    STAGE_B(bb ^ 1, 0, t + 1);
    MIDBAR(); DO_MFMA(0, 0); ENDBAR();
    // phase 2: quadrant (0,1); A0 slot of this buffer is free -> tile t+2
    LOADB(1);
    STAGE_A(bb, 0, t + 2);
    MIDBAR(); DO_MFMA(0, 1); ENDBAR();
    // phase 3: quadrant (1,1); B1 slot free -> tile t+2
    LOADA(1);
    STAGE_B(bb, 1, t + 2);
    MIDBAR(); DO_MFMA(1, 1); ENDBAR();
    // phase 4: quadrant (1,0); A1 slot free -> tile t+2; counted vmcnt
    LOADB(0);
    STAGE_A(bb, 1, t + 2);
    MIDBAR(); DO_MFMA(1, 0); ENDBAR_VM();
  }

  // epilogue: acc + bias (+gelu) -> Cout
  #pragma unroll
  for (int qb = 0; qb < 2; ++qb)
    #pragma unroll
    for (int g = 0; g < 2; ++g) {
      int col = n0 + qb * 128 + wc32 + g * 16 + lrow;
      float bc = bias[col];
      #pragma unroll
      for (int qa = 0; qa < 2; ++qa)
        #pragma unroll
        for (int f = 0; f < 4; ++f)
          #pragma unroll
          for (int rg = 0; rg < 4; ++rg) {
            int row = m0 + qa * 128 + wr64 + f * 16 + quad * 4 + rg;
            float v = acc[qa][qb][f][g][rg] + bc;
            if (EPI == 0) {
              float gl = 0.5f * v * (1.0f + erff(v * 0.70710678118654752f));
              ((bf16*)Cout)[(size_t)row * N + col] = __float2bfloat16(gl);
            } else {
              ((float*)Cout)[(size_t)row * N + col] = v;
            }
          }
    }
}

extern "C" void kernel_launch(void* const* d_in, const int* in_sizes, int n_in,
                              void* d_out, int out_size, void* d_ws, size_t ws_size,
                              hipStream_t stream) {
  const float* x   = (const float*)d_in[0];
  const float* pos = (const float*)d_in[1];
  const float* w1  = (const float*)d_in[2];
  const float* b1  = (const float*)d_in[3];
  const float* w2  = (const float*)d_in[4];
  const float* b2  = (const float*)d_in[5];

  uint8_t* wsp = (uint8_t*)d_ws;
  size_t off = 0;
  auto alloc = [&](size_t bytes) -> void* {
    void* p = wsp + off;
    off += (bytes + 255) & ~(size_t)255;
    return p;
  };
  double* m_a  = (double*)alloc((size_t)BB * P0 * HD * 8);      // 26.9 MB
  double* m_b  = (double*)alloc((size_t)BB * NSTR * HD * 8);    // 13.5 MB
  double* rn   = (double*)alloc((size_t)BB * P0 * 8);
  double* nmax = (double*)alloc((size_t)BB * NSTR * 8);
  int*    nidx = (int*)alloc((size_t)BB * NSTR * 4);
  int*    eidx = (int*)alloc((size_t)BB * NSTR * 4);
  double* pmax = (double*)alloc((size_t)BB * MAXCB * SCB * 8);  // 1.18 MB
  int*    pidx = (int*)alloc((size_t)BB * MAXCB * SCB * 4);
  int*    amap = (int*)alloc((size_t)BB * P0 * 4);
  int*    szs  = (int*)alloc((size_t)BB * TT * 4);
  bf16*   xb   = (bf16*)alloc((size_t)BB * TT * CC * 2);        // 18.9 MB
  bf16*   w1t  = (bf16*)alloc((size_t)HH * CC * 2);             // 8.3 MB
  bf16*   w2t  = (bf16*)alloc((size_t)HH * HH * 2);             // 25.7 MB
  bf16*   hb   = (bf16*)alloc((size_t)BB * TT * HH * 2);        // 58.7 MB

  // accum (fp32, 37.75 MB) reuses m_a+m_b (40.3 MB) -- both dead after rounds
  float* accum = (float*)m_a;

  k_init<<<BB * P0, 128, 0, stream>>>(x, pos, m_a, amap);
  dim3 tb(32, 8);
  k_transpose<<<dim3(HH / 32, CC / 32), tb, 0, stream>>>(w1, w1t, CC, HH);
  k_transpose<<<dim3(HH / 32, HH / 32), tb, 0, stream>>>(w2, w2t, HH, HH);

  struct Rnd { int t, s, d, r, unm, tnew; };
  const Rnd R[3] = {{729, 365, 364, 364, 1, 365},
                    {365, 183, 182, 182, 1, 183},
                    {183,  92,  91,  55, 37, 128}};
  double* msrc[3] = {m_a, m_b, m_a};
  double* mdst[3] = {m_b, m_a, m_b};

  for (int rr = 0; rr < 3; ++rr) {
    Rnd q = R[rr];
    k_rnorm<<<BB * q.t, 64, 0, stream>>>(msrc[rr], rn, q.t);
    int rt = (q.s + 63) / 64, ct = (q.d + 63) / 64;
    dim3 sg(rt, ct, BB);
    k_score2<<<sg, 256, 0, stream>>>(msrc[rr], rn, pmax, pidx, q.t, q.s, q.d);
    k_colred<<<BB, 512, 0, stream>>>(pmax, pidx, nmax, nidx, q.s, ct);
    if (rr == 0)      k_sort<512><<<BB, 512, 0, stream>>>(nmax, eidx, q.s);
    else if (rr == 1) k_sort<256><<<BB, 256, 0, stream>>>(nmax, eidx, q.s);
    else              k_sort<128><<<BB, 128, 0, stream>>>(nmax, eidx, q.s);
    k_mapround<<<BB, 512, 0, stream>>>(eidx, nidx, amap, q.t, q.s, q.r, q.unm);
    if (rr < 2) {  // metric for next round only
      size_t tg = (size_t)BB * q.tnew * HD;
      k_gather_d<<<(tg + 255) / 256, 256, 0, stream>>>(msrc[rr], mdst[rr], eidx, q.t, q.r, q.unm, q.tnew);
      size_t ts = (size_t)BB * q.r * HD;
      k_scatter_d<<<(ts + 255) / 256, 256, 0, stream>>>(msrc[rr], mdst[rr], eidx, nidx, q.t, q.r, q.unm, q.tnew);
    }
  }

  // assembly: sizes -> clear accum -> scatter-add rows -> normalize+cast
  k_sizes<<<BB, 256, 0, stream>>>(amap, szs);
  k_clear<<<4096, 256, 0, stream>>>((float4*)accum, BB * TT * CC / 4);
  k_scatter_rows<<<(BB * P0) / 4, 256, 0, stream>>>(x, pos, amap, accum);
  k_normalize<<<(BB * TT) / 4, 256, 0, stream>>>(accum, szs, xb);

  // GEMM1: (8192 x 1152) x (1152 x 3584) -> gelu -> hb (bf16)
  k_gemm<0><<<dim3(HH / 256, (BB * TT) / 256), 512, 0, stream>>>(
      (const u16*)xb, (const u16*)w1t, b1, hb, BB * TT, HH, CC);
  // GEMM2: (8192 x 3584) x (3584 x 3584) -> + b2 -> d_out (fp32)
  k_gemm<1><<<dim3(HH / 256, (BB * TT) / 256), 512, 0, stream>>>(
      (const u16*)hb, (const u16*)w2t, b2, d_out, BB * TT, HH, HH);
}

// Round 3
// 1203.681 us; speedup vs baseline: 1.7641x; 1.7641x over previous
//
#include <hip/hip_runtime.h>
#include <hip/hip_bf16.h>
#include <stdint.h>

// Problem constants
#define BB 64
#define P0 729
#define CC 1152
#define HD 72        // CC / 16 heads
#define NHEAD 16
#define HH 3584
#define TT 128
#define NSTR 365     // max src count, stride for per-round index arrays
#define SCB 384      // padded row stride for partial-argmax buffers
#define MAXCB 6      // max column blocks (ceil(364/64))

typedef __hip_bfloat16 bf16;
typedef unsigned short u16;
typedef __attribute__((ext_vector_type(8))) short short8;
typedef __attribute__((ext_vector_type(4))) float floatx4;

__device__ inline u16 f2bf(float v) {
  bf16 h = __float2bfloat16(v);
  return *(u16*)&h;
}

__device__ inline void load_lds16(const void* g, void* l) {
  __builtin_amdgcn_global_load_lds(
      (const __attribute__((address_space(1))) uint32_t*)g,
      (__attribute__((address_space(3))) uint32_t*)l, 16, 0, 0);
}

// ---------------- init: fp64 head-mean of (x+pos), amap = identity ----------------
__global__ __launch_bounds__(128)
void k_init(const float* __restrict__ x, const float* __restrict__ pos,
            double* __restrict__ mo, int* __restrict__ amap) {
  __shared__ float xs[CC], ps[CC];
  int bp = blockIdx.x;           // b*729+p
  int p = bp % P0;
  int tid = threadIdx.x;         // 128
  const float4* xr = (const float4*)(x + (size_t)bp * CC);
  const float4* pr = (const float4*)(pos + (size_t)p * CC);
  for (int idx = tid; idx < CC / 4; idx += 128) {
    ((float4*)xs)[idx] = xr[idx];
    ((float4*)ps)[idx] = pr[idx];
  }
  __syncthreads();
  if (tid < HD) {
    double s = 0.0;
    #pragma unroll
    for (int h = 0; h < NHEAD; ++h) {
      int c = h * HD + tid;
      s += (double)xs[c] + (double)ps[c];
    }
    mo[(size_t)bp * HD + tid] = s * (1.0 / 16.0);
  }
  if (tid == 0) amap[bp] = p;
}

// ---------------- 1/||m|| per token (fp64) ----------------
__global__ void k_rnorm(const double* __restrict__ m, double* __restrict__ rn, int t) {
  int bi = blockIdx.x;           // b*t + i
  int lane = threadIdx.x;        // 64
  const double* row = m + (size_t)bi * HD;
  double v = 0.0;
  if (lane < HD) { double a = row[lane]; v = a * a; }
  if (lane < HD - 64) { double a = row[lane + 64]; v += a * a; }
  for (int off = 32; off; off >>= 1) v += __shfl_down(v, off, 64);
  if (lane == 0) {
    int b = bi / t, i = bi % t;
    rn[b * P0 + i] = 1.0 / sqrt(v);
  }
}

// ---------------- fp64 scores, 64x64 tile, 4x4 per thread ----------------
// Emits per-column-strip (max, first-argmax) partials; k_colred folds strips.
__global__ __launch_bounds__(256)
void k_score2(const double* __restrict__ m, const double* __restrict__ rn,
              double* __restrict__ pmax, int* __restrict__ pidx,
              int t, int s, int d) {
  __shared__ double sL[64][37];
  __shared__ double sD[64][37];
  int b = blockIdx.z;
  int i0 = blockIdx.x * 64, j0 = blockIdx.y * 64;
  int tid = threadIdx.x;
  int tx = tid & 15, ty = tid >> 4;
  double acc[4][4] = {};
  for (int kc = 0; kc < HD; kc += 36) {
    for (int idx = tid; idx < 64 * 36; idx += 256) {
      int row = idx / 36, k = idx - row * 36;
      int i = i0 + row;
      sL[row][k] = (i < s) ? m[((size_t)b * t + 2 * i) * HD + kc + k] : 0.0;
      int j = j0 + row;
      sD[row][k] = (j < d) ? m[((size_t)b * t + 2 * j + 1) * HD + kc + k] : 0.0;
    }
    __syncthreads();
    #pragma unroll 6
    for (int k = 0; k < 36; ++k) {
      double la[4], ld[4];
      #pragma unroll
      for (int a = 0; a < 4; ++a) la[a] = sL[ty + 16 * a][k];
      #pragma unroll
      for (int c = 0; c < 4; ++c) ld[c] = sD[tx + 16 * c][k];
      #pragma unroll
      for (int a = 0; a < 4; ++a)
        #pragma unroll
        for (int c = 0; c < 4; ++c)
          acc[a][c] += la[a] * ld[c];
    }
    __syncthreads();
  }
  #pragma unroll
  for (int a = 0; a < 4; ++a) {
    int i = i0 + ty + 16 * a;
    double rni = (i < s) ? rn[b * P0 + 2 * i] : 0.0;
    double best = -1e300; int bj = 0x7fffffff;
    #pragma unroll
    for (int c = 0; c < 4; ++c) {
      int j = j0 + tx + 16 * c;                       // ascending j per c
      double sc = (j < d) ? acc[a][c] * rni * rn[b * P0 + 2 * j + 1] : -1e300;
      if (sc > best) { best = sc; bj = j; }           // strict > keeps first max
    }
    for (int off = 8; off; off >>= 1) {
      double ov = __shfl_down(best, off, 16);
      int oj = __shfl_down(bj, off, 16);
      if (ov > best || (ov == best && oj < bj)) { best = ov; bj = oj; }
    }
    if (tx == 0 && i < s) {
      pmax[((size_t)b * MAXCB + blockIdx.y) * SCB + i] = best;
      pidx[((size_t)b * MAXCB + blockIdx.y) * SCB + i] = bj;
    }
  }
}

// ---------------- fold column-strip partials (ascending j, first-max) ----------
__global__ void k_colred(const double* __restrict__ pmax, const int* __restrict__ pidx,
                         double* __restrict__ nmax, int* __restrict__ nidx,
                         int s, int ncb) {
  int b = blockIdx.x, i = threadIdx.x;   // 512 >= s
  if (i >= s) return;
  double best = -1e300; int bj = 0x7fffffff;
  for (int cb = 0; cb < ncb; ++cb) {
    double v = pmax[((size_t)b * MAXCB + cb) * SCB + i];
    int j = pidx[((size_t)b * MAXCB + cb) * SCB + i];
    if (v > best) { best = v; bj = j; }  // cb ascending = j ascending
  }
  nmax[b * NSTR + i] = best; nidx[b * NSTR + i] = bj;
}

// ---------------- stable descending argsort (bitonic, idx tiebreak) ----------------
template <int SZ>
__global__ __launch_bounds__(512)
void k_sort(const double* __restrict__ nmax, int* __restrict__ eidx, int s) {
  __shared__ double v[SZ];
  __shared__ int ix[SZ];
  int b = blockIdx.x, tid = threadIdx.x;
  if (tid < s) { v[tid] = nmax[b * NSTR + tid]; ix[tid] = tid; }
  else { v[tid] = -1e308; ix[tid] = 1024 + tid; }
  __syncthreads();
  for (int k = 2; k <= SZ; k <<= 1)
    for (int j = k >> 1; j > 0; j >>= 1) {
      int l = tid ^ j;
      if (l > tid) {
        double va = v[tid], vb = v[l]; int ia = ix[tid], ib = ix[l];
        bool b_before_a = (vb > va) || (vb == va && ib < ia);
        bool a_before_b = (va > vb) || (va == vb && ia < ib);
        bool dir = ((tid & k) == 0);
        bool sw = dir ? b_before_a : a_before_b;
        if (sw) { v[tid] = vb; v[l] = va; ix[tid] = ib; ix[l] = ia; }
      }
      __syncthreads();
    }
  if (tid < s) eidx[b * NSTR + tid] = ix[tid];
}

// ---------------- compose per-round old->new map into amap (orig token -> slot) ----
__global__ __launch_bounds__(512)
void k_mapround(const int* __restrict__ eidx, const int* __restrict__ nidx,
                int* __restrict__ amap, int t, int s, int r, int unm) {
  __shared__ int pos_of[NSTR];
  __shared__ int rmap[P0];
  int b = blockIdx.x, tid = threadIdx.x;
  for (int q = tid; q < s; q += 512) pos_of[eidx[b * NSTR + q]] = q;
  __syncthreads();
  for (int j = tid; j < t; j += 512) {
    int nm;
    if (j & 1) {
      nm = unm + (j >> 1);                      // odd token = dst jd -> unm + jd
    } else {
      int i = j >> 1;                           // even token = src i
      int q = pos_of[i];
      nm = (q >= r) ? (q - r)                   // unmerged: position in unm block
                    : (unm + nidx[b * NSTR + i]); // merged into its dst
    }
    rmap[j] = nm;
  }
  __syncthreads();
  for (int p = tid; p < P0; p += 512) {
    int cur = amap[b * P0 + p];
    amap[b * P0 + p] = rmap[cur];
  }
}

// ---------------- fp64 metric merge: gather then scatter-add ----------------
__global__ void k_gather_d(const double* __restrict__ mo, double* __restrict__ mn,
                           const int* __restrict__ eidx,
                           int t, int r, int unm, int tnew) {
  size_t idx = (size_t)blockIdx.x * 256 + threadIdx.x;
  size_t total = (size_t)BB * tnew * HD;
  if (idx >= total) return;
  int k = idx % HD;
  int o = (idx / HD) % tnew;
  int b = idx / ((size_t)HD * tnew);
  int tok = (o < unm) ? 2 * eidx[b * NSTR + r + o] : 2 * (o - unm) + 1;
  mn[idx] = mo[((size_t)b * t + tok) * HD + k];
}

__global__ void k_scatter_d(const double* __restrict__ mo, double* __restrict__ mn,
                            const int* __restrict__ eidx, const int* __restrict__ nidx,
                            int t, int r, int unm, int tnew) {
  size_t idx = (size_t)blockIdx.x * 256 + threadIdx.x;
  size_t total = (size_t)BB * r * HD;
  if (idx >= total) return;
  int k = idx % HD;
  int q = (idx / HD) % r;
  int b = idx / ((size_t)HD * r);
  int si = eidx[b * NSTR + q];
  int di = nidx[b * NSTR + si];
  atomicAdd(&mn[((size_t)b * tnew + unm + di) * HD + k],
            mo[((size_t)b * t + 2 * si) * HD + k]);
}

// ---------------- CSR build: counts (=sizes), offsets, member lists ----------------
__global__ __launch_bounds__(256)
void k_buildcsr(const int* __restrict__ amap, int* __restrict__ sizes,
                int* __restrict__ offs, int* __restrict__ list) {
  __shared__ int cnt[TT], off_s[TT], cur[TT];
  int b = blockIdx.x, tid = threadIdx.x;
  if (tid < TT) { cnt[tid] = 0; cur[tid] = 0; }
  __syncthreads();
  for (int p = tid; p < P0; p += 256) atomicAdd(&cnt[amap[b * P0 + p]], 1);
  __syncthreads();
  if (tid == 0) {
    int acc = 0;
    for (int o = 0; o < TT; ++o) { off_s[o] = acc; acc += cnt[o]; }
  }
  __syncthreads();
  if (tid < TT) { sizes[b * TT + tid] = cnt[tid]; offs[b * TT + tid] = off_s[tid]; }
  for (int p = tid; p < P0; p += 256) {
    int o = amap[b * P0 + p];
    int pos = atomicAdd(&cur[o], 1);
    list[b * P0 + off_s[o] + pos] = p;
  }
}

// ---------------- final assembly: sum assigned (x+pos) rows, /size, -> bf16 --------
// Latency fix vs old version: member list preloaded to LDS (no dependent index
// load in the chain) and member loop unrolled x4 (8+ independent float4 loads
// in flight per lane instead of 2).
__global__ __launch_bounds__(256)
void k_assemble(const float* __restrict__ x, const float* __restrict__ pos,
                const int* __restrict__ sizes, const int* __restrict__ offs,
                const int* __restrict__ list, bf16* __restrict__ xb) {
  __shared__ int ml[P0];
  int o = blockIdx.x, b = blockIdx.y, tid = threadIdx.x;
  int n = sizes[b * TT + o];
  int off = offs[b * TT + o];
  for (int i = tid; i < n; i += 256) ml[i] = list[b * P0 + off + i];
  __syncthreads();
  const int C4 = CC / 4;  // 288 float4 per row; thread covers tid and tid+256 (if <32)
  const bool two = (tid < C4 - 256);
  float4 a0 = {0.f, 0.f, 0.f, 0.f}, a1 = {0.f, 0.f, 0.f, 0.f};
  int i = 0;
  for (; i + 4 <= n; i += 4) {
    int p0 = ml[i], p1 = ml[i + 1], p2 = ml[i + 2], p3 = ml[i + 3];
    const float4* x0 = (const float4*)(x + ((size_t)b * P0 + p0) * CC);
    const float4* x1 = (const float4*)(x + ((size_t)b * P0 + p1) * CC);
    const float4* x2 = (const float4*)(x + ((size_t)b * P0 + p2) * CC);
    const float4* x3 = (const float4*)(x + ((size_t)b * P0 + p3) * CC);
    const float4* q0 = (const float4*)(pos + (size_t)p0 * CC);
    const float4* q1 = (const float4*)(pos + (size_t)p1 * CC);
    const float4* q2 = (const float4*)(pos + (size_t)p2 * CC);
    const float4* q3 = (const float4*)(pos + (size_t)p3 * CC);
    float4 v0 = x0[tid], v1 = x1[tid], v2 = x2[tid], v3 = x3[tid];
    float4 w0 = q0[tid], w1 = q1[tid], w2 = q2[tid], w3 = q3[tid];
    a0.x += (v0.x + w0.x) + (v1.x + w1.x) + (v2.x + w2.x) + (v3.x + w3.x);
    a0.y += (v0.y + w0.y) + (v1.y + w1.y) + (v2.y + w2.y) + (v3.y + w3.y);
    a0.z += (v0.z + w0.z) + (v1.z + w1.z) + (v2.z + w2.z) + (v3.z + w3.z);
    a0.w += (v0.w + w0.w) + (v1.w + w1.w) + (v2.w + w2.w) + (v3.w + w3.w);
    if (two) {
      float4 u0 = x0[tid + 256], u1 = x1[tid + 256], u2 = x2[tid + 256], u3 = x3[tid + 256];
      float4 s0 = q0[tid + 256], s1 = q1[tid + 256], s2 = q2[tid + 256], s3 = q3[tid + 256];
      a1.x += (u0.x + s0.x) + (u1.x + s1.x) + (u2.x + s2.x) + (u3.x + s3.x);
      a1.y += (u0.y + s0.y) + (u1.y + s1.y) + (u2.y + s2.y) + (u3.y + s3.y);
      a1.z += (u0.z + s0.z) + (u1.z + s1.z) + (u2.z + s2.z) + (u3.z + s3.z);
      a1.w += (u0.w + s0.w) + (u1.w + s1.w) + (u2.w + s2.w) + (u3.w + s3.w);
    }
  }
  for (; i < n; ++i) {
    int p = ml[i];
    const float4* xr = (const float4*)(x + ((size_t)b * P0 + p) * CC);
    const float4* pr = (const float4*)(pos + (size_t)p * CC);
    float4 v = xr[tid], w = pr[tid];
    a0.x += v.x + w.x; a0.y += v.y + w.y; a0.z += v.z + w.z; a0.w += v.w + w.w;
    if (two) {
      float4 v1 = xr[tid + 256], w1 = pr[tid + 256];
      a1.x += v1.x + w1.x; a1.y += v1.y + w1.y; a1.z += v1.z + w1.z; a1.w += v1.w + w1.w;
    }
  }
  float inv = 1.0f / (float)n;
  bf16* orow = xb + ((size_t)b * TT + o) * CC;
  ushort4 pk;
  pk.x = f2bf(a0.x * inv);
  pk.y = f2bf(a0.y * inv);
  pk.z = f2bf(a0.z * inv);
  pk.w = f2bf(a0.w * inv);
  ((ushort4*)orow)[tid] = pk;
  if (two) {
    ushort4 pk1;
    pk1.x = f2bf(a1.x * inv);
    pk1.y = f2bf(a1.y * inv);
    pk1.z = f2bf(a1.z * inv);
    pk1.w = f2bf(a1.w * inv);
    ((ushort4*)orow)[tid + 256] = pk1;
  }
}

// ---------------- transpose + cast weights: (K,N) fp32 -> (N,K) bf16 ----------------
__global__ void k_transpose(const float* __restrict__ w, bf16* __restrict__ wt,
                            int K, int N) {
  __shared__ float tile[32][33];
  int n0 = blockIdx.x * 32, k0 = blockIdx.y * 32;
  int tx = threadIdx.x, ty = threadIdx.y;   // 32 x 8
  #pragma unroll
  for (int yy = 0; yy < 32; yy += 8)
    tile[ty + yy][tx] = w[(size_t)(k0 + ty + yy) * N + n0 + tx];
  __syncthreads();
  #pragma unroll
  for (int yy = 0; yy < 32; yy += 8)
    wt[(size_t)(n0 + ty + yy) * K + k0 + tx] = __float2bfloat16(tile[tx][ty + yy]);
}

// =====================================================================
// 256x256 8-phase bf16 MFMA GEMM (T2 swizzle + T3/T4 counted vmcnt + T5)
// A (M,K) row-major bf16, Bt (N,K) row-major bf16.
// 512 threads = 8 waves (2 M x 4 N); per-wave 64x32 piece of each of the
// four 128x128 C-quadrants. BK=64, double-buffered LDS (128 KiB), one
// half-tile (128x64) staged per phase, vmcnt(6) once per K-tile at phase 4.
// LDS swizzle: col16 ^= (row&7) (16B granularity); inverse applied to the
// GLOBAL source address so global_load_lds' linear dest stays legal.
// EPI 0: out = bf16(gelu_exact(acc + bias))   EPI 1: out = fp32(acc + bias)
// =====================================================================

#define SBAR __builtin_amdgcn_sched_barrier(0)

#define STAGE_A(BUF, HHF, KT) do {                                        \
    int ktc_ = (KT) < nkt ? (KT) : nkt - 1;                               \
    const u16* s_ = gA + (size_t)(HHF) * 128 * K + ktc_ * 64;             \
    u16* d_ = dA + (BUF) * 16384 + (HHF) * 8192;                          \
    load_lds16(s_, d_);                                                   \
    load_lds16(s_ + (size_t)64 * K, d_ + 4096);                           \
  } while (0)

#define STAGE_B(BUF, HHF, KT) do {                                        \
    int ktc_ = (KT) < nkt ? (KT) : nkt - 1;                               \
    const u16* s_ = gB + (size_t)(HHF) * 128 * K + ktc_ * 64;             \
    u16* d_ = dB + (BUF) * 16384 + (HHF) * 8192;                          \
    load_lds16(s_, d_);                                                   \
    load_lds16(s_ + (size_t)64 * K, d_ + 4096);                           \
  } while (0)

#define LOADA(QA) do {                                                    \
    _Pragma("unroll")                                                     \
    for (int f_ = 0; f_ < 4; ++f_) {                                      \
      const u16* p_ = Ab + ((QA) * 128 + wr64 + f_ * 16 + lrow) * 64;     \
      af[f_][0] = *(const short8*)(p_ + swo0);                            \
      af[f_][1] = *(const short8*)(p_ + swo1);                            \
    }                                                                     \
  } while (0)

#define LOADB(QB) do {                                                    \
    _Pragma("unroll")                                                     \
    for (int g_ = 0; g_ < 2; ++g_) {                                      \
      const u16* p_ = Bb + ((QB) * 128 + wc32 + g_ * 16 + lrow) * 64;     \
      bfr[g_][0] = *(const short8*)(p_ + swo0);                           \
      bfr[g_][1] = *(const short8*)(p_ + swo1);                           \
    }                                                                     \
  } while (0)

#define DO_MFMA(QA, QB) do {                                              \
    _Pragma("unroll")                                                     \
    for (int ks_ = 0; ks_ < 2; ++ks_)                                     \
      _Pragma("unroll")                                                   \
      for (int f_ = 0; f_ < 4; ++f_)                                      \
        _Pragma("unroll")                                                 \
        for (int g_ = 0; g_ < 2; ++g_)                                    \
          acc[QA][QB][f_][g_] = __builtin_amdgcn_mfma_f32_16x16x32_bf16(  \
              af[f_][ks_], bfr[g_][ks_], acc[QA][QB][f_][g_], 0, 0, 0);   \
  } while (0)

#define MIDBAR() do {                                                     \
    SBAR;                                                                 \
    __builtin_amdgcn_s_barrier();                                         \
    asm volatile("s_waitcnt lgkmcnt(0)" ::: "memory");                    \
    SBAR;                                                                 \
    __builtin_amdgcn_s_setprio(1);                                        \
  } while (0)

#define ENDBAR() do {                                                     \
    __builtin_amdgcn_s_setprio(0);                                        \
    SBAR;                                                                 \
    __builtin_amdgcn_s_barrier();                                         \
    SBAR;                                                                 \
  } while (0)

#define ENDBAR_VM() do {                                                  \
    __builtin_amdgcn_s_setprio(0);                                        \
    SBAR;                                                                 \
    asm volatile("s_waitcnt vmcnt(6)" ::: "memory");                      \
    SBAR;                                                                 \
    __builtin_amdgcn_s_barrier();                                         \
    SBAR;                                                                 \
  } while (0)

template <int EPI>
__global__ __launch_bounds__(512, 2)
void k_gemm(const u16* __restrict__ A, const u16* __restrict__ Bt,
            const float* __restrict__ bias, void* __restrict__ Cout,
            int M, int N, int K) {
  __shared__ u16 sAall[32768];   // [buf][256 rows][64] bf16, 64 KiB
  __shared__ u16 sBall[32768];   // 64 KiB
  (void)M;
  const int tid = threadIdx.x;
  const int m0 = blockIdx.y * 256, n0 = blockIdx.x * 256;
  const int wave = tid >> 6, lane = tid & 63;
  const int wr64 = (wave >> 2) * 64;   // wave's rows within a quadrant
  const int wc32 = (wave & 3) * 32;    // wave's cols within a quadrant
  const int quad = lane >> 4, lrow = lane & 15;
  const int sw = lrow & 7;             // row&7 == lrow&7 for all frag rows
  const int swo0 = ((quad ^ sw)) << 3;        // ks=0 swizzled u16 offset
  const int swo1 = (((quad | 4) ^ sw)) << 3;  // ks=1
  const int nkt = K >> 6;              // K-tiles of 64

  // staging geometry: thread covers rows r and r+64 of a 128x64 half-tile;
  // source col16 pre-swizzled so linear LDS dest + swizzled ds_read agree.
  const int r = tid >> 3;
  const int c16 = (tid & 7) ^ (r & 7);
  const u16* gA = A + (size_t)(m0 + r) * K + c16 * 8;
  const u16* gB = Bt + (size_t)(n0 + r) * K + c16 * 8;
  u16* dA = sAall + (tid << 3);
  u16* dB = sBall + (tid << 3);

  floatx4 acc[2][2][4][2] = {};   // [qa][qb][mfrag][nfrag]
  short8 af[4][2], bfr[2][2];     // [frag][kstep]

  // prologue: tile0 fully (A0,B1,A1,B0) + tile1 all but B0 -> 14 loads;
  // vmcnt(6) leaves exactly tile1's {A0,B1,A1} in flight (steady state).
  STAGE_A(0, 0, 0); STAGE_B(0, 1, 0); STAGE_A(0, 1, 0); STAGE_B(0, 0, 0);
  STAGE_A(1, 0, 1); STAGE_B(1, 1, 1); STAGE_A(1, 1, 1);
  SBAR;
  asm volatile("s_waitcnt vmcnt(6)" ::: "memory");
  SBAR;
  __builtin_amdgcn_s_barrier();
  SBAR;

  for (int t = 0; t < nkt; ++t) {
    const int bb = t & 1;
    const u16* Ab = sAall + bb * 16384;
    const u16* Bb = sBall + bb * 16384;
    // phase 1: quadrant (0,0); stage B-half0 of tile t+1 into other buffer
    LOADA(0); LOADB(0);
    STAGE_B(bb ^ 1, 0, t + 1);
    MIDBAR(); DO_MFMA(0, 0); ENDBAR();
    // phase 2: quadrant (0,1); A0 slot of this buffer is free -> tile t+2
    LOADB(1);
    STAGE_A(bb, 0, t + 2);
    MIDBAR(); DO_MFMA(0, 1); ENDBAR();
    // phase 3: quadrant (1,1); B1 slot free -> tile t+2
    LOADA(1);
    STAGE_B(bb, 1, t + 2);
    MIDBAR(); DO_MFMA(1, 1); ENDBAR();
    // phase 4: quadrant (1,0); A1 slot free -> tile t+2; counted vmcnt
    LOADB(0);
    STAGE_A(bb, 1, t + 2);
    MIDBAR(); DO_MFMA(1, 0); ENDBAR_VM();
  }

  // epilogue: acc + bias (+gelu) -> Cout
  #pragma unroll
  for (int qb = 0; qb < 2; ++qb)
    #pragma unroll
    for (int g = 0; g < 2; ++g) {
      int col = n0 + qb * 128 + wc32 + g * 16 + lrow;
      float bc = bias[col];
      #pragma unroll
      for (int qa = 0; qa < 2; ++qa)
        #pragma unroll
        for (int f = 0; f < 4; ++f)
          #pragma unroll
          for (int rg = 0; rg < 4; ++rg) {
            int row = m0 + qa * 128 + wr64 + f * 16 + quad * 4 + rg;
            float v = acc[qa][qb][f][g][rg] + bc;
            if (EPI == 0) {
              float gl = 0.5f * v * (1.0f + erff(v * 0.70710678118654752f));
              ((bf16*)Cout)[(size_t)row * N + col] = __float2bfloat16(gl);
            } else {
              ((float*)Cout)[(size_t)row * N + col] = v;
            }
          }
    }
}

extern "C" void kernel_launch(void* const* d_in, const int* in_sizes, int n_in,
                              void* d_out, int out_size, void* d_ws, size_t ws_size,
                              hipStream_t stream) {
  const float* x   = (const float*)d_in[0];
  const float* pos = (const float*)d_in[1];
  const float* w1  = (const float*)d_in[2];
  const float* b1  = (const float*)d_in[3];
  const float* w2  = (const float*)d_in[4];
  const float* b2  = (const float*)d_in[5];

  uint8_t* wsp = (uint8_t*)d_ws;
  size_t off = 0;
  auto alloc = [&](size_t bytes) -> void* {
    void* p = wsp + off;
    off += (bytes + 255) & ~(size_t)255;
    return p;
  };
  double* m_a  = (double*)alloc((size_t)BB * P0 * HD * 8);      // 26.9 MB
  double* m_b  = (double*)alloc((size_t)BB * NSTR * HD * 8);    // 13.5 MB
  double* rn   = (double*)alloc((size_t)BB * P0 * 8);
  double* nmax = (double*)alloc((size_t)BB * NSTR * 8);
  int*    nidx = (int*)alloc((size_t)BB * NSTR * 4);
  int*    eidx = (int*)alloc((size_t)BB * NSTR * 4);
  double* pmax = (double*)alloc((size_t)BB * MAXCB * SCB * 8);  // 1.18 MB
  int*    pidx = (int*)alloc((size_t)BB * MAXCB * SCB * 4);
  int*    amap = (int*)alloc((size_t)BB * P0 * 4);
  int*    szs  = (int*)alloc((size_t)BB * TT * 4);
  int*    offs = (int*)alloc((size_t)BB * TT * 4);
  int*    list = (int*)alloc((size_t)BB * P0 * 4);
  bf16*   xb   = (bf16*)alloc((size_t)BB * TT * CC * 2);        // 18.9 MB
  bf16*   w1t  = (bf16*)alloc((size_t)HH * CC * 2);             // 8.3 MB
  bf16*   w2t  = (bf16*)alloc((size_t)HH * HH * 2);             // 25.7 MB
  bf16*   hb   = (bf16*)alloc((size_t)BB * TT * HH * 2);        // 58.7 MB

  k_init<<<BB * P0, 128, 0, stream>>>(x, pos, m_a, amap);
  dim3 tb(32, 8);
  k_transpose<<<dim3(HH / 32, CC / 32), tb, 0, stream>>>(w1, w1t, CC, HH);
  k_transpose<<<dim3(HH / 32, HH / 32), tb, 0, stream>>>(w2, w2t, HH, HH);

  struct Rnd { int t, s, d, r, unm, tnew; };
  const Rnd R[3] = {{729, 365, 364, 364, 1, 365},
                    {365, 183, 182, 182, 1, 183},
                    {183,  92,  91,  55, 37, 128}};
  double* msrc[3] = {m_a, m_b, m_a};
  double* mdst[3] = {m_b, m_a, m_b};

  for (int rr = 0; rr < 3; ++rr) {
    Rnd q = R[rr];
    k_rnorm<<<BB * q.t, 64, 0, stream>>>(msrc[rr], rn, q.t);
    int rt = (q.s + 63) / 64, ct = (q.d + 63) / 64;
    dim3 sg(rt, ct, BB);
    k_score2<<<sg, 256, 0, stream>>>(msrc[rr], rn, pmax, pidx, q.t, q.s, q.d);
    k_colred<<<BB, 512, 0, stream>>>(pmax, pidx, nmax, nidx, q.s, ct);
    if (rr == 0)      k_sort<512><<<BB, 512, 0, stream>>>(nmax, eidx, q.s);
    else if (rr == 1) k_sort<256><<<BB, 256, 0, stream>>>(nmax, eidx, q.s);
    else              k_sort<128><<<BB, 128, 0, stream>>>(nmax, eidx, q.s);
    k_mapround<<<BB, 512, 0, stream>>>(eidx, nidx, amap, q.t, q.s, q.r, q.unm);
    if (rr < 2) {  // metric for next round only
      size_t tg = (size_t)BB * q.tnew * HD;
      k_gather_d<<<(tg + 255) / 256, 256, 0, stream>>>(msrc[rr], mdst[rr], eidx, q.t, q.r, q.unm, q.tnew);
      size_t ts = (size_t)BB * q.r * HD;
      k_scatter_d<<<(ts + 255) / 256, 256, 0, stream>>>(msrc[rr], mdst[rr], eidx, nidx, q.t, q.r, q.unm, q.tnew);
    }
  }

  k_buildcsr<<<BB, 256, 0, stream>>>(amap, szs, offs, list);
  k_assemble<<<dim3(TT, BB), 256, 0, stream>>>(x, pos, szs, offs, list, xb);

  // GEMM1: (8192 x 1152) x (1152 x 3584) -> gelu -> hb (bf16)
  k_gemm<0><<<dim3(HH / 256, (BB * TT) / 256), 512, 0, stream>>>(
      (const u16*)xb, (const u16*)w1t, b1, hb, BB * TT, HH, CC);
  // GEMM2: (8192 x 3584) x (3584 x 3584) -> + b2 -> d_out (fp32)
  k_gemm<1><<<dim3(HH / 256, (BB * TT) / 256), 512, 0, stream>>>(
      (const u16*)hb, (const u16*)w2t, b2, d_out, BB * TT, HH, HH);
}

// Round 4
// 1123.608 us; speedup vs baseline: 1.8898x; 1.0713x over previous
//
#include <hip/hip_runtime.h>
#include <hip/hip_bf16.h>
#include <stdint.h>

// Problem constants
#define BB 64
#define P0 729
#define CC 1152
#define HD 72        // CC / 16 heads
#define NHEAD 16
#define HH 3584
#define TT 128
#define NSTR 365     // max src count, stride for per-round index arrays
#define SCB 384      // padded row stride for partial-argmax buffers
#define MAXCB 6      // max column blocks (ceil(364/64))

typedef __hip_bfloat16 bf16;
typedef unsigned short u16;
typedef __attribute__((ext_vector_type(8))) short short8;
typedef __attribute__((ext_vector_type(4))) float floatx4;

__device__ inline u16 f2bf(float v) {
  bf16 h = __float2bfloat16(v);
  return *(u16*)&h;
}

__device__ inline void load_lds16(const void* g, void* l) {
  __builtin_amdgcn_global_load_lds(
      (const __attribute__((address_space(1))) uint32_t*)g,
      (__attribute__((address_space(3))) uint32_t*)l, 16, 0, 0);
}

// ---------------- init: fp64 head-mean of (x+pos), amap = identity ----------------
__global__ __launch_bounds__(128)
void k_init(const float* __restrict__ x, const float* __restrict__ pos,
            double* __restrict__ mo, int* __restrict__ amap) {
  __shared__ float xs[CC], ps[CC];
  int bp = blockIdx.x;           // b*729+p
  int p = bp % P0;
  int tid = threadIdx.x;         // 128
  const float4* xr = (const float4*)(x + (size_t)bp * CC);
  const float4* pr = (const float4*)(pos + (size_t)p * CC);
  for (int idx = tid; idx < CC / 4; idx += 128) {
    ((float4*)xs)[idx] = xr[idx];
    ((float4*)ps)[idx] = pr[idx];
  }
  __syncthreads();
  if (tid < HD) {
    double s = 0.0;
    #pragma unroll
    for (int h = 0; h < NHEAD; ++h) {
      int c = h * HD + tid;
      s += (double)xs[c] + (double)ps[c];
    }
    mo[(size_t)bp * HD + tid] = s * (1.0 / 16.0);
  }
  if (tid == 0) amap[bp] = p;
}

// ---------------- 1/||m|| per token (fp64) ----------------
__global__ void k_rnorm(const double* __restrict__ m, double* __restrict__ rn, int t) {
  int bi = blockIdx.x;           // b*t + i
  int lane = threadIdx.x;        // 64
  const double* row = m + (size_t)bi * HD;
  double v = 0.0;
  if (lane < HD) { double a = row[lane]; v = a * a; }
  if (lane < HD - 64) { double a = row[lane + 64]; v += a * a; }
  for (int off = 32; off; off >>= 1) v += __shfl_down(v, off, 64);
  if (lane == 0) {
    int b = bi / t, i = bi % t;
    rn[b * P0 + i] = 1.0 / sqrt(v);
  }
}

// ---------------- fp64 scores, 64x64 tile, 4x4 per thread ----------------
// Emits per-column-strip (max, first-argmax) partials; k_colred folds strips.
__global__ __launch_bounds__(256)
void k_score2(const double* __restrict__ m, const double* __restrict__ rn,
              double* __restrict__ pmax, int* __restrict__ pidx,
              int t, int s, int d) {
  __shared__ double sL[64][37];
  __shared__ double sD[64][37];
  int b = blockIdx.z;
  int i0 = blockIdx.x * 64, j0 = blockIdx.y * 64;
  int tid = threadIdx.x;
  int tx = tid & 15, ty = tid >> 4;
  double acc[4][4] = {};
  for (int kc = 0; kc < HD; kc += 36) {
    for (int idx = tid; idx < 64 * 36; idx += 256) {
      int row = idx / 36, k = idx - row * 36;
      int i = i0 + row;
      sL[row][k] = (i < s) ? m[((size_t)b * t + 2 * i) * HD + kc + k] : 0.0;
      int j = j0 + row;
      sD[row][k] = (j < d) ? m[((size_t)b * t + 2 * j + 1) * HD + kc + k] : 0.0;
    }
    __syncthreads();
    #pragma unroll 6
    for (int k = 0; k < 36; ++k) {
      double la[4], ld[4];
      #pragma unroll
      for (int a = 0; a < 4; ++a) la[a] = sL[ty + 16 * a][k];
      #pragma unroll
      for (int c = 0; c < 4; ++c) ld[c] = sD[tx + 16 * c][k];
      #pragma unroll
      for (int a = 0; a < 4; ++a)
        #pragma unroll
        for (int c = 0; c < 4; ++c)
          acc[a][c] += la[a] * ld[c];
    }
    __syncthreads();
  }
  #pragma unroll
  for (int a = 0; a < 4; ++a) {
    int i = i0 + ty + 16 * a;
    double rni = (i < s) ? rn[b * P0 + 2 * i] : 0.0;
    double best = -1e300; int bj = 0x7fffffff;
    #pragma unroll
    for (int c = 0; c < 4; ++c) {
      int j = j0 + tx + 16 * c;                       // ascending j per c
      double sc = (j < d) ? acc[a][c] * rni * rn[b * P0 + 2 * j + 1] : -1e300;
      if (sc > best) { best = sc; bj = j; }           // strict > keeps first max
    }
    for (int off = 8; off; off >>= 1) {
      double ov = __shfl_down(best, off, 16);
      int oj = __shfl_down(bj, off, 16);
      if (ov > best || (ov == best && oj < bj)) { best = ov; bj = oj; }
    }
    if (tx == 0 && i < s) {
      pmax[((size_t)b * MAXCB + blockIdx.y) * SCB + i] = best;
      pidx[((size_t)b * MAXCB + blockIdx.y) * SCB + i] = bj;
    }
  }
}

// ---------------- fold column-strip partials (ascending j, first-max) ----------
__global__ void k_colred(const double* __restrict__ pmax, const int* __restrict__ pidx,
                         double* __restrict__ nmax, int* __restrict__ nidx,
                         int s, int ncb) {
  int b = blockIdx.x, i = threadIdx.x;   // 512 >= s
  if (i >= s) return;
  double best = -1e300; int bj = 0x7fffffff;
  for (int cb = 0; cb < ncb; ++cb) {
    double v = pmax[((size_t)b * MAXCB + cb) * SCB + i];
    int j = pidx[((size_t)b * MAXCB + cb) * SCB + i];
    if (v > best) { best = v; bj = j; }  // cb ascending = j ascending
  }
  nmax[b * NSTR + i] = best; nidx[b * NSTR + i] = bj;
}

// ---------------- stable descending argsort (bitonic, idx tiebreak) ----------------
template <int SZ>
__global__ __launch_bounds__(512)
void k_sort(const double* __restrict__ nmax, int* __restrict__ eidx, int s) {
  __shared__ double v[SZ];
  __shared__ int ix[SZ];
  int b = blockIdx.x, tid = threadIdx.x;
  if (tid < s) { v[tid] = nmax[b * NSTR + tid]; ix[tid] = tid; }
  else { v[tid] = -1e308; ix[tid] = 1024 + tid; }
  __syncthreads();
  for (int k = 2; k <= SZ; k <<= 1)
    for (int j = k >> 1; j > 0; j >>= 1) {
      int l = tid ^ j;
      if (l > tid) {
        double va = v[tid], vb = v[l]; int ia = ix[tid], ib = ix[l];
        bool b_before_a = (vb > va) || (vb == va && ib < ia);
        bool a_before_b = (va > vb) || (va == vb && ia < ib);
        bool dir = ((tid & k) == 0);
        bool sw = dir ? b_before_a : a_before_b;
        if (sw) { v[tid] = vb; v[l] = va; ix[tid] = ib; ix[l] = ia; }
      }
      __syncthreads();
    }
  if (tid < s) eidx[b * NSTR + tid] = ix[tid];
}

// ---------------- compose per-round old->new map into amap (orig token -> slot) ----
__global__ __launch_bounds__(512)
void k_mapround(const int* __restrict__ eidx, const int* __restrict__ nidx,
                int* __restrict__ amap, int t, int s, int r, int unm) {
  __shared__ int pos_of[NSTR];
  __shared__ int rmap[P0];
  int b = blockIdx.x, tid = threadIdx.x;
  for (int q = tid; q < s; q += 512) pos_of[eidx[b * NSTR + q]] = q;
  __syncthreads();
  for (int j = tid; j < t; j += 512) {
    int nm;
    if (j & 1) {
      nm = unm + (j >> 1);                      // odd token = dst jd -> unm + jd
    } else {
      int i = j >> 1;                           // even token = src i
      int q = pos_of[i];
      nm = (q >= r) ? (q - r)                   // unmerged: position in unm block
                    : (unm + nidx[b * NSTR + i]); // merged into its dst
    }
    rmap[j] = nm;
  }
  __syncthreads();
  for (int p = tid; p < P0; p += 512) {
    int cur = amap[b * P0 + p];
    amap[b * P0 + p] = rmap[cur];
  }
}

// ---------------- fp64 metric merge: gather then scatter-add ----------------
__global__ void k_gather_d(const double* __restrict__ mo, double* __restrict__ mn,
                           const int* __restrict__ eidx,
                           int t, int r, int unm, int tnew) {
  size_t idx = (size_t)blockIdx.x * 256 + threadIdx.x;
  size_t total = (size_t)BB * tnew * HD;
  if (idx >= total) return;
  int k = idx % HD;
  int o = (idx / HD) % tnew;
  int b = idx / ((size_t)HD * tnew);
  int tok = (o < unm) ? 2 * eidx[b * NSTR + r + o] : 2 * (o - unm) + 1;
  mn[idx] = mo[((size_t)b * t + tok) * HD + k];
}

__global__ void k_scatter_d(const double* __restrict__ mo, double* __restrict__ mn,
                            const int* __restrict__ eidx, const int* __restrict__ nidx,
                            int t, int r, int unm, int tnew) {
  size_t idx = (size_t)blockIdx.x * 256 + threadIdx.x;
  size_t total = (size_t)BB * r * HD;
  if (idx >= total) return;
  int k = idx % HD;
  int q = (idx / HD) % r;
  int b = idx / ((size_t)HD * r);
  int si = eidx[b * NSTR + q];
  int di = nidx[b * NSTR + si];
  atomicAdd(&mn[((size_t)b * tnew + unm + di) * HD + k],
            mo[((size_t)b * t + 2 * si) * HD + k]);
}

// ---------------- CSR build: counts (=sizes), offsets, member lists ----------------
__global__ __launch_bounds__(256)
void k_buildcsr(const int* __restrict__ amap, int* __restrict__ sizes,
                int* __restrict__ offs, int* __restrict__ list) {
  __shared__ int cnt[TT], off_s[TT], cur[TT];
  int b = blockIdx.x, tid = threadIdx.x;
  if (tid < TT) { cnt[tid] = 0; cur[tid] = 0; }
  __syncthreads();
  for (int p = tid; p < P0; p += 256) atomicAdd(&cnt[amap[b * P0 + p]], 1);
  __syncthreads();
  if (tid == 0) {
    int acc = 0;
    for (int o = 0; o < TT; ++o) { off_s[o] = acc; acc += cnt[o]; }
  }
  __syncthreads();
  if (tid < TT) { sizes[b * TT + tid] = cnt[tid]; offs[b * TT + tid] = off_s[tid]; }
  for (int p = tid; p < P0; p += 256) {
    int o = amap[b * P0 + p];
    int pos = atomicAdd(&cur[o], 1);
    list[b * P0 + off_s[o] + pos] = p;
  }
}

// ---------------- final assembly: sum assigned (x+pos) rows, /size, -> bf16 --------
// Member list preloaded to LDS (no dependent index load in the chain) and
// member loop unrolled x4 (8+ independent float4 loads in flight per lane).
__global__ __launch_bounds__(256)
void k_assemble(const float* __restrict__ x, const float* __restrict__ pos,
                const int* __restrict__ sizes, const int* __restrict__ offs,
                const int* __restrict__ list, bf16* __restrict__ xb) {
  __shared__ int ml[P0];
  int o = blockIdx.x, b = blockIdx.y, tid = threadIdx.x;
  int n = sizes[b * TT + o];
  int off = offs[b * TT + o];
  for (int i = tid; i < n; i += 256) ml[i] = list[b * P0 + off + i];
  __syncthreads();
  const int C4 = CC / 4;  // 288 float4 per row; thread covers tid and tid+256 (if <32)
  const bool two = (tid < C4 - 256);
  float4 a0 = {0.f, 0.f, 0.f, 0.f}, a1 = {0.f, 0.f, 0.f, 0.f};
  int i = 0;
  for (; i + 4 <= n; i += 4) {
    int p0 = ml[i], p1 = ml[i + 1], p2 = ml[i + 2], p3 = ml[i + 3];
    const float4* x0 = (const float4*)(x + ((size_t)b * P0 + p0) * CC);
    const float4* x1 = (const float4*)(x + ((size_t)b * P0 + p1) * CC);
    const float4* x2 = (const float4*)(x + ((size_t)b * P0 + p2) * CC);
    const float4* x3 = (const float4*)(x + ((size_t)b * P0 + p3) * CC);
    const float4* q0 = (const float4*)(pos + (size_t)p0 * CC);
    const float4* q1 = (const float4*)(pos + (size_t)p1 * CC);
    const float4* q2 = (const float4*)(pos + (size_t)p2 * CC);
    const float4* q3 = (const float4*)(pos + (size_t)p3 * CC);
    float4 v0 = x0[tid], v1 = x1[tid], v2 = x2[tid], v3 = x3[tid];
    float4 w0 = q0[tid], w1 = q1[tid], w2 = q2[tid], w3 = q3[tid];
    a0.x += (v0.x + w0.x) + (v1.x + w1.x) + (v2.x + w2.x) + (v3.x + w3.x);
    a0.y += (v0.y + w0.y) + (v1.y + w1.y) + (v2.y + w2.y) + (v3.y + w3.y);
    a0.z += (v0.z + w0.z) + (v1.z + w1.z) + (v2.z + w2.z) + (v3.z + w3.z);
    a0.w += (v0.w + w0.w) + (v1.w + w1.w) + (v2.w + w2.w) + (v3.w + w3.w);
    if (two) {
      float4 u0 = x0[tid + 256], u1 = x1[tid + 256], u2 = x2[tid + 256], u3 = x3[tid + 256];
      float4 s0 = q0[tid + 256], s1 = q1[tid + 256], s2 = q2[tid + 256], s3 = q3[tid + 256];
      a1.x += (u0.x + s0.x) + (u1.x + s1.x) + (u2.x + s2.x) + (u3.x + s3.x);
      a1.y += (u0.y + s0.y) + (u1.y + s1.y) + (u2.y + s2.y) + (u3.y + s3.y);
      a1.z += (u0.z + s0.z) + (u1.z + s1.z) + (u2.z + s2.z) + (u3.z + s3.z);
      a1.w += (u0.w + s0.w) + (u1.w + s1.w) + (u2.w + s2.w) + (u3.w + s3.w);
    }
  }
  for (; i < n; ++i) {
    int p = ml[i];
    const float4* xr = (const float4*)(x + ((size_t)b * P0 + p) * CC);
    const float4* pr = (const float4*)(pos + (size_t)p * CC);
    float4 v = xr[tid], w = pr[tid];
    a0.x += v.x + w.x; a0.y += v.y + w.y; a0.z += v.z + w.z; a0.w += v.w + w.w;
    if (two) {
      float4 v1 = xr[tid + 256], w1 = pr[tid + 256];
      a1.x += v1.x + w1.x; a1.y += v1.y + w1.y; a1.z += v1.z + w1.z; a1.w += v1.w + w1.w;
    }
  }
  float inv = 1.0f / (float)n;
  bf16* orow = xb + ((size_t)b * TT + o) * CC;
  ushort4 pk;
  pk.x = f2bf(a0.x * inv);
  pk.y = f2bf(a0.y * inv);
  pk.z = f2bf(a0.z * inv);
  pk.w = f2bf(a0.w * inv);
  ((ushort4*)orow)[tid] = pk;
  if (two) {
    ushort4 pk1;
    pk1.x = f2bf(a1.x * inv);
    pk1.y = f2bf(a1.y * inv);
    pk1.z = f2bf(a1.z * inv);
    pk1.w = f2bf(a1.w * inv);
    ((ushort4*)orow)[tid + 256] = pk1;
  }
}

// ---------------- transpose + cast weights: (K,N) fp32 -> (N,K) bf16 ----------------
__global__ void k_transpose(const float* __restrict__ w, bf16* __restrict__ wt,
                            int K, int N) {
  __shared__ float tile[32][33];
  int n0 = blockIdx.x * 32, k0 = blockIdx.y * 32;
  int tx = threadIdx.x, ty = threadIdx.y;   // 32 x 8
  #pragma unroll
  for (int yy = 0; yy < 32; yy += 8)
    tile[ty + yy][tx] = w[(size_t)(k0 + ty + yy) * N + n0 + tx];
  __syncthreads();
  #pragma unroll
  for (int yy = 0; yy < 32; yy += 8)
    wt[(size_t)(n0 + ty + yy) * K + k0 + tx] = __float2bfloat16(tile[tx][ty + yy]);
}

// =====================================================================
// 256x256 bf16 MFMA GEMM, 4 phases/K-tile, ds_reads pipelined ONE PHASE
// AHEAD of their consuming MFMA with counted lgkmcnt (DS completes in
// order), counted vmcnt(4) at phase 3, T2 LDS swizzle, T5 setprio,
// bijective XCD-aware block swizzle.
// Per-K-tile read schedule (per wave, ds_read_b128):
//   ph1: rB0(4)+rB1(4) issued, lgkm(4) drains rA0(prev ph4)+rB0, keeps rB1
//   ph2: rA1(8) issued, lgkm(8) drains rB1, keeps rA1
//   ph3: no reads, vmcnt(4) pre-barrier (tile t+1 landed), lgkm(0) drains rA1
//   ph4: rA0'(8) from other buffer (next tile), NO lgkm wait
// MFMA quadrant order: (0,0) (0,1) (1,1) (1,0) using af0/bf0, af0/bf1,
// af1/bf1, af1/bf0 -- every operand drained >=1 phase before use.
// EPI 0: out = bf16(gelu_exact(acc + bias))   EPI 1: out = fp32(acc + bias)
// =====================================================================

#define SBAR __builtin_amdgcn_sched_barrier(0)

#define STAGE_A(BUF, HHF, KT) do {                                        \
    int ktc_ = (KT) < nkt ? (KT) : nkt - 1;                               \
    const u16* s_ = gA + (size_t)(HHF) * 128 * K + ktc_ * 64;             \
    u16* d_ = dA + (BUF) * 16384 + (HHF) * 8192;                          \
    load_lds16(s_, d_);                                                   \
    load_lds16(s_ + (size_t)64 * K, d_ + 4096);                           \
  } while (0)

#define STAGE_B(BUF, HHF, KT) do {                                        \
    int ktc_ = (KT) < nkt ? (KT) : nkt - 1;                               \
    const u16* s_ = gB + (size_t)(HHF) * 128 * K + ktc_ * 64;             \
    u16* d_ = dB + (BUF) * 16384 + (HHF) * 8192;                          \
    load_lds16(s_, d_);                                                   \
    load_lds16(s_ + (size_t)64 * K, d_ + 4096);                           \
  } while (0)

#define LOAD_A(DST, BUF, QA) do {                                        \
    _Pragma("unroll")                                                     \
    for (int f_ = 0; f_ < 4; ++f_) {                                      \
      const u16* p_ = (BUF) + ((QA) * 128 + wr64 + f_ * 16 + lrow) * 64;  \
      DST[f_][0] = *(const short8*)(p_ + swo0);                           \
      DST[f_][1] = *(const short8*)(p_ + swo1);                           \
    }                                                                     \
  } while (0)

#define LOAD_B(DST, BUF, QB) do {                                        \
    _Pragma("unroll")                                                     \
    for (int g_ = 0; g_ < 2; ++g_) {                                      \
      const u16* p_ = (BUF) + ((QB) * 128 + wc32 + g_ * 16 + lrow) * 64;  \
      DST[g_][0] = *(const short8*)(p_ + swo0);                           \
      DST[g_][1] = *(const short8*)(p_ + swo1);                           \
    }                                                                     \
  } while (0)

#define DO_MFMA(AF, BF, QA, QB) do {                                      \
    _Pragma("unroll")                                                     \
    for (int ks_ = 0; ks_ < 2; ++ks_)                                     \
      _Pragma("unroll")                                                   \
      for (int f_ = 0; f_ < 4; ++f_)                                      \
        _Pragma("unroll")                                                 \
        for (int g_ = 0; g_ < 2; ++g_)                                    \
          acc[QA][QB][f_][g_] = __builtin_amdgcn_mfma_f32_16x16x32_bf16(  \
              AF[f_][ks_], BF[g_][ks_], acc[QA][QB][f_][g_], 0, 0, 0);    \
  } while (0)

#define PH_BAR() do { SBAR; __builtin_amdgcn_s_barrier(); SBAR; } while (0)

template <int EPI>
__global__ __launch_bounds__(512, 2)
void k_gemm(const u16* __restrict__ A, const u16* __restrict__ Bt,
            const float* __restrict__ bias, void* __restrict__ Cout,
            int M, int N, int K) {
  __shared__ u16 sAall[32768];   // [buf][256 rows][64] bf16, 64 KiB
  __shared__ u16 sBall[32768];   // 64 KiB
  (void)M;
  const int tid = threadIdx.x;
  // bijective XCD-aware block swizzle (8 XCDs; nwg % 8 handled via m204 form)
  const int nwg = gridDim.x * gridDim.y;
  const int wg = blockIdx.y * gridDim.x + blockIdx.x;
  const int qx = nwg >> 3, rx = nwg & 7;
  const int xcd = wg & 7, loc = wg >> 3;
  const int swz = (xcd < rx ? xcd * (qx + 1) : rx * (qx + 1) + (xcd - rx) * qx) + loc;
  const int m0 = (swz / gridDim.x) * 256, n0 = (swz % gridDim.x) * 256;
  const int wave = tid >> 6, lane = tid & 63;
  const int wr64 = (wave >> 2) * 64;   // wave's rows within a quadrant
  const int wc32 = (wave & 3) * 32;    // wave's cols within a quadrant
  const int quad = lane >> 4, lrow = lane & 15;
  const int sw = lrow & 7;             // row&7 == lrow&7 for all frag rows
  const int swo0 = ((quad ^ sw)) << 3;        // ks=0 swizzled u16 offset
  const int swo1 = (((quad | 4) ^ sw)) << 3;  // ks=1
  const int nkt = K >> 6;              // K-tiles of 64

  // staging geometry: thread covers rows r and r+64 of a 128x64 half-tile;
  // source col16 pre-swizzled so linear LDS dest + swizzled ds_read agree.
  const int r = tid >> 3;
  const int c16 = (tid & 7) ^ (r & 7);
  const u16* gA = A + (size_t)(m0 + r) * K + c16 * 8;
  const u16* gB = Bt + (size_t)(n0 + r) * K + c16 * 8;
  u16* dA = sAall + (tid << 3);
  u16* dB = sBall + (tid << 3);

  floatx4 acc[2][2][4][2] = {};   // [qa][qb][mfrag][nfrag]
  short8 af0[4][2], af1[4][2];    // A quadrant frags [frag][kstep]
  short8 bf0[2][2], bf1[2][2];    // B quadrant frags

  // prologue: tile0 fully (A0,B1,A1,B0) + tile1 {A0,B1,A1} -> 14 loads;
  // vmcnt(6) leaves tile1's 3 half-tiles in flight (steady state).
  STAGE_A(0, 0, 0); STAGE_B(0, 1, 0); STAGE_A(0, 1, 0); STAGE_B(0, 0, 0);
  STAGE_A(1, 0, 1); STAGE_B(1, 1, 1); STAGE_A(1, 1, 1);
  SBAR;
  asm volatile("s_waitcnt vmcnt(6)" ::: "memory");
  SBAR;
  __builtin_amdgcn_s_barrier();
  SBAR;
  LOAD_A(af0, sAall, 0);   // pre-loop rA0 for tile 0 (8 reads, in flight)

  for (int t = 0; t < nkt; ++t) {
    const int bb = t & 1;
    const u16* Ab = sAall + bb * 16384;
    const u16* Bb = sBall + bb * 16384;
    const u16* Ao = sAall + (bb ^ 1) * 16384;
    // ---- phase 1: MFMA(0,0)[af0,bf0]; issue rB0,rB1; stage B0(t+1)->other
    LOAD_B(bf0, Bb, 0);
    LOAD_B(bf1, Bb, 1);
    STAGE_B(bb ^ 1, 0, t + 1);
    SBAR; __builtin_amdgcn_s_barrier();
    asm volatile("s_waitcnt lgkmcnt(4)" ::: "memory");  // drain rA0+rB0, keep rB1
    SBAR;
    __builtin_amdgcn_s_setprio(1);
    DO_MFMA(af0, bf0, 0, 0);
    __builtin_amdgcn_s_setprio(0);
    PH_BAR();
    // ---- phase 2: MFMA(0,1)[af0,bf1]; issue rA1; stage A0(t+2)->this
    LOAD_A(af1, Ab, 1);
    STAGE_A(bb, 0, t + 2);
    SBAR; __builtin_amdgcn_s_barrier();
    asm volatile("s_waitcnt lgkmcnt(8)" ::: "memory");  // drain rB1, keep rA1
    SBAR;
    __builtin_amdgcn_s_setprio(1);
    DO_MFMA(af0, bf1, 0, 1);
    __builtin_amdgcn_s_setprio(0);
    PH_BAR();
    // ---- phase 3: MFMA(1,1)[af1,bf1]; no reads; stage B1(t+2); vmcnt gate
    STAGE_B(bb, 1, t + 2);
    SBAR;
    asm volatile("s_waitcnt vmcnt(4)" ::: "memory");    // tile t+1 landed
    SBAR;
    __builtin_amdgcn_s_barrier();
    asm volatile("s_waitcnt lgkmcnt(0)" ::: "memory");  // drain rA1
    SBAR;
    __builtin_amdgcn_s_setprio(1);
    DO_MFMA(af1, bf1, 1, 1);
    __builtin_amdgcn_s_setprio(0);
    PH_BAR();
    // ---- phase 4: MFMA(1,0)[af1,bf0]; issue rA0' (next tile); no lgkm wait
    LOAD_A(af0, Ao, 0);
    STAGE_A(bb, 1, t + 2);
    SBAR; __builtin_amdgcn_s_barrier(); SBAR;
    __builtin_amdgcn_s_setprio(1);
    DO_MFMA(af1, bf0, 1, 0);
    __builtin_amdgcn_s_setprio(0);
    PH_BAR();
  }

  // epilogue: acc + bias (+gelu) -> Cout
  #pragma unroll
  for (int qb = 0; qb < 2; ++qb)
    #pragma unroll
    for (int g = 0; g < 2; ++g) {
      int col = n0 + qb * 128 + wc32 + g * 16 + lrow;
      float bc = bias[col];
      #pragma unroll
      for (int qa = 0; qa < 2; ++qa)
        #pragma unroll
        for (int f = 0; f < 4; ++f)
          #pragma unroll
          for (int rg = 0; rg < 4; ++rg) {
            int row = m0 + qa * 128 + wr64 + f * 16 + quad * 4 + rg;
            float v = acc[qa][qb][f][g][rg] + bc;
            if (EPI == 0) {
              float gl = 0.5f * v * (1.0f + erff(v * 0.70710678118654752f));
              ((bf16*)Cout)[(size_t)row * N + col] = __float2bfloat16(gl);
            } else {
              ((float*)Cout)[(size_t)row * N + col] = v;
            }
          }
    }
}

extern "C" void kernel_launch(void* const* d_in, const int* in_sizes, int n_in,
                              void* d_out, int out_size, void* d_ws, size_t ws_size,
                              hipStream_t stream) {
  const float* x   = (const float*)d_in[0];
  const float* pos = (const float*)d_in[1];
  const float* w1  = (const float*)d_in[2];
  const float* b1  = (const float*)d_in[3];
  const float* w2  = (const float*)d_in[4];
  const float* b2  = (const float*)d_in[5];

  uint8_t* wsp = (uint8_t*)d_ws;
  size_t off = 0;
  auto alloc = [&](size_t bytes) -> void* {
    void* p = wsp + off;
    off += (bytes + 255) & ~(size_t)255;
    return p;
  };
  double* m_a  = (double*)alloc((size_t)BB * P0 * HD * 8);      // 26.9 MB
  double* m_b  = (double*)alloc((size_t)BB * NSTR * HD * 8);    // 13.5 MB
  double* rn   = (double*)alloc((size_t)BB * P0 * 8);
  double* nmax = (double*)alloc((size_t)BB * NSTR * 8);
  int*    nidx = (int*)alloc((size_t)BB * NSTR * 4);
  int*    eidx = (int*)alloc((size_t)BB * NSTR * 4);
  double* pmax = (double*)alloc((size_t)BB * MAXCB * SCB * 8);  // 1.18 MB
  int*    pidx = (int*)alloc((size_t)BB * MAXCB * SCB * 4);
  int*    amap = (int*)alloc((size_t)BB * P0 * 4);
  int*    szs  = (int*)alloc((size_t)BB * TT * 4);
  int*    offs = (int*)alloc((size_t)BB * TT * 4);
  int*    list = (int*)alloc((size_t)BB * P0 * 4);
  bf16*   xb   = (bf16*)alloc((size_t)BB * TT * CC * 2);        // 18.9 MB
  bf16*   w1t  = (bf16*)alloc((size_t)HH * CC * 2);             // 8.3 MB
  bf16*   w2t  = (bf16*)alloc((size_t)HH * HH * 2);             // 25.7 MB
  bf16*   hb   = (bf16*)alloc((size_t)BB * TT * HH * 2);        // 58.7 MB

  k_init<<<BB * P0, 128, 0, stream>>>(x, pos, m_a, amap);
  dim3 tb(32, 8);
  k_transpose<<<dim3(HH / 32, CC / 32), tb, 0, stream>>>(w1, w1t, CC, HH);
  k_transpose<<<dim3(HH / 32, HH / 32), tb, 0, stream>>>(w2, w2t, HH, HH);

  struct Rnd { int t, s, d, r, unm, tnew; };
  const Rnd R[3] = {{729, 365, 364, 364, 1, 365},
                    {365, 183, 182, 182, 1, 183},
                    {183,  92,  91,  55, 37, 128}};
  double* msrc[3] = {m_a, m_b, m_a};
  double* mdst[3] = {m_b, m_a, m_b};

  for (int rr = 0; rr < 3; ++rr) {
    Rnd q = R[rr];
    k_rnorm<<<BB * q.t, 64, 0, stream>>>(msrc[rr], rn, q.t);
    int rt = (q.s + 63) / 64, ct = (q.d + 63) / 64;
    dim3 sg(rt, ct, BB);
    k_score2<<<sg, 256, 0, stream>>>(msrc[rr], rn, pmax, pidx, q.t, q.s, q.d);
    k_colred<<<BB, 512, 0, stream>>>(pmax, pidx, nmax, nidx, q.s, ct);
    if (rr == 0)      k_sort<512><<<BB, 512, 0, stream>>>(nmax, eidx, q.s);
    else if (rr == 1) k_sort<256><<<BB, 256, 0, stream>>>(nmax, eidx, q.s);
    else              k_sort<128><<<BB, 128, 0, stream>>>(nmax, eidx, q.s);
    k_mapround<<<BB, 512, 0, stream>>>(eidx, nidx, amap, q.t, q.s, q.r, q.unm);
    if (rr < 2) {  // metric for next round only
      size_t tg = (size_t)BB * q.tnew * HD;
      k_gather_d<<<(tg + 255) / 256, 256, 0, stream>>>(msrc[rr], mdst[rr], eidx, q.t, q.r, q.unm, q.tnew);
      size_t ts = (size_t)BB * q.r * HD;
      k_scatter_d<<<(ts + 255) / 256, 256, 0, stream>>>(msrc[rr], mdst[rr], eidx, nidx, q.t, q.r, q.unm, q.tnew);
    }
  }

  k_buildcsr<<<BB, 256, 0, stream>>>(amap, szs, offs, list);
  k_assemble<<<dim3(TT, BB), 256, 0, stream>>>(x, pos, szs, offs, list, xb);

  // GEMM1: (8192 x 1152) x (1152 x 3584) -> gelu -> hb (bf16)
  k_gemm<0><<<dim3(HH / 256, (BB * TT) / 256), 512, 0, stream>>>(
      (const u16*)xb, (const u16*)w1t, b1, hb, BB * TT, HH, CC);
  // GEMM2: (8192 x 3584) x (3584 x 3584) -> + b2 -> d_out (fp32)
  k_gemm<1><<<dim3(HH / 256, (BB * TT) / 256), 512, 0, stream>>>(
      (const u16*)hb, (const u16*)w2t, b2, d_out, BB * TT, HH, HH);
}